// Round 2
// baseline (27.390 us; speedup 1.0000x reference)
//
#include <hip/hip_runtime.h>

// out[row] = dot(x[row*768 : (row+1)*768], W) + b[0], row in [0, B*N).
// 8 rows per wave: per k-chunk (k=0..2) issue 8 independent dwordx4 loads
// (128B/lane in flight) before consuming -> deep memory pipeline.
// Merged shuffle reduction: 10 shfl total for 8 row-sums.
constexpr int ROWS = 8;

__global__ __launch_bounds__(256, 6) void patchconv_kernel(
    const float* __restrict__ x,
    const float* __restrict__ W,
    const float* __restrict__ b,
    float* __restrict__ out,
    int nrows) {
  const int gtid = blockIdx.x * blockDim.x + threadIdx.x;
  const int wave = gtid >> 6;
  const int lane = threadIdx.x & 63;
  const int base = wave * ROWS;
  if (base >= nrows) return;

  const float4* __restrict__ wr = reinterpret_cast<const float4*>(W);
  float4 wv[3];
#pragma unroll
  for (int k = 0; k < 3; ++k) wv[k] = wr[lane + k * 64];

  float sums[ROWS];
#pragma unroll
  for (int r = 0; r < ROWS; ++r) sums[r] = 0.f;

  // base row group is 8 rows * 768 floats = 1536 float4, contiguous.
  const float4* __restrict__ xr =
      reinterpret_cast<const float4*>(x + (size_t)base * 768);

#pragma unroll
  for (int k = 0; k < 3; ++k) {
    float4 xv[ROWS];
#pragma unroll
    for (int r = 0; r < ROWS; ++r) xv[r] = xr[r * 192 + k * 64 + lane];
#pragma unroll
    for (int r = 0; r < ROWS; ++r) {
      sums[r] += xv[r].x * wv[k].x + xv[r].y * wv[k].y +
                 xv[r].z * wv[k].z + xv[r].w * wv[k].w;
    }
  }

  // Merged reduction. merge(a,b,mask): lanes with (lane&mask)==0 continue
  // carrying a (reduced over that bit), lanes with bit set carry b.
  auto merge = [&](float a, float bb, int mask) -> float {
    const bool up = (lane & mask) != 0;
    const float sel = up ? a : bb;          // send what the partner needs
    const float got = __shfl_xor(sel, mask, 64);
    const float mine = up ? bb : a;
    return mine + got;
  };

  float m0 = merge(sums[0], sums[4], 32);   // idx 0 / 4 by bit5
  float m1 = merge(sums[1], sums[5], 32);   // idx 1 / 5
  float m2 = merge(sums[2], sums[6], 32);   // idx 2 / 6
  float m3 = merge(sums[3], sums[7], 32);   // idx 3 / 7
  float n0 = merge(m0, m1, 16);             // idx 4*b5 + b4
  float n1 = merge(m2, m3, 16);             // idx 4*b5 + b4 + 2
  float p  = merge(n0, n1, 8);              // idx 4*b5 + b4 + 2*b3
  p += __shfl_xor(p, 4, 64);
  p += __shfl_xor(p, 2, 64);
  p += __shfl_xor(p, 1, 64);

  if ((lane & 7) == 0) {
    const int idx = 4 * ((lane >> 5) & 1) + ((lane >> 4) & 1) + 2 * ((lane >> 3) & 1);
    if (base + idx < nrows) out[base + idx] = p + b[0];
  }
}

extern "C" void kernel_launch(void* const* d_in, const int* in_sizes, int n_in,
                              void* d_out, int out_size, void* d_ws, size_t ws_size,
                              hipStream_t stream) {
  const float* x = (const float*)d_in[0];   // [B, N, C, P, P] fp32
  const float* W = (const float*)d_in[1];   // [C, P, P] fp32
  const float* b = (const float*)d_in[2];   // [1] fp32
  float* out = (float*)d_out;               // [B, N] fp32

  const int nrows = out_size;               // 50176
  const int wavesNeeded = (nrows + ROWS - 1) / ROWS;   // 6272
  const int blocks = (wavesNeeded + 3) / 4;            // 4 waves/block
  patchconv_kernel<<<blocks, 256, 0, stream>>>(x, W, b, out, nrows);
}

// Round 4
// 25.979 us; speedup vs baseline: 1.0543x; 1.0543x over previous
//
#include <hip/hip_runtime.h>

// out[row] = dot(x[row*768 : row*768+768], W[0:768]) + b[0]
// One wave (64 lanes) per row. Lane i loads float4 at element offsets
// i*4 + k*256 -> fully coalesced 1KB segments. x is streamed with
// nontemporal loads (read-once data, no reuse).
// Native clang vector type: __builtin_nontemporal_load rejects the
// HIP_vector_type struct wrapper but accepts ext_vector_type.
typedef float f4 __attribute__((ext_vector_type(4)));

__global__ __launch_bounds__(256) void patchconv_kernel(
    const float* __restrict__ x,
    const float* __restrict__ W,
    const float* __restrict__ b,
    float* __restrict__ out,
    int nrows) {
  const int gtid = blockIdx.x * blockDim.x + threadIdx.x;
  const int wave = gtid >> 6;
  const int lane = threadIdx.x & 63;
  if (wave >= nrows) return;

  const f4* __restrict__ xr =
      reinterpret_cast<const f4*>(x + (size_t)wave * 768);
  const f4* __restrict__ wr = reinterpret_cast<const f4*>(W);

  float sum = 0.f;
#pragma unroll
  for (int k = 0; k < 3; ++k) {
    const f4 xv = __builtin_nontemporal_load(&xr[lane + k * 64]);
    const f4 wv = wr[lane + k * 64];
    sum += xv.x * wv.x + xv.y * wv.y + xv.z * wv.z + xv.w * wv.w;
  }

  // 64-lane wave reduction
#pragma unroll
  for (int off = 32; off > 0; off >>= 1)
    sum += __shfl_down(sum, off, 64);

  if (lane == 0) out[wave] = sum + b[0];
}

extern "C" void kernel_launch(void* const* d_in, const int* in_sizes, int n_in,
                              void* d_out, int out_size, void* d_ws, size_t ws_size,
                              hipStream_t stream) {
  const float* x = (const float*)d_in[0];   // [B, N, C, P, P] fp32
  const float* W = (const float*)d_in[1];   // [C, P, P] fp32
  const float* b = (const float*)d_in[2];   // [1] fp32
  float* out = (float*)d_out;               // [B, N] fp32

  const int nrows = out_size;               // 256*196 = 50176
  const int wavesPerBlock = 4;              // 256 threads
  const int blocks = (nrows + wavesPerBlock - 1) / wavesPerBlock;
  patchconv_kernel<<<blocks, 256, 0, stream>>>(x, W, b, out, nrows);
}